// Round 15
// baseline (19.819 us; speedup 1.0000x reference)
//
#include <hip/hip_runtime.h>
#include <cmath>

// KFIoU loss: pred (NP x 5), target (NT x 5) -> loss (NP x NT) f32.
//
// Numerics (established R1-R14): harness ref is a FLOAT32 numpy evaluation.
// Recipe: identical f32 op order, no fma contraction, correctly-rounded f32
// sin/cos (double Taylor for |r|<=1 -- bit-identical since R12), and:
//   RULE 1 (upstream of det_sig cancellation: box params, i/k/sig chain):
//     CR-or-negligible-misround -> refined rcp + Markstein fma.
//   RULE 2 (downstream of the cancellation: sqrt, denom, final divide):
//     1-2 ulp deviations invisible (R10: raw v_sqrt_f32 kept absmax
//     bit-identical). This round extends RULE 2: denom reciprocal is raw
//     v_rcp_f32 (1 ulp), no Newton.
//
// Perf (this round): amortize per-thread fixed costs. ROWS 16->32 halves
// the prologue share (f64 sincos + box chain recomputed per block) and
// block ramp/drain count; unroll-4 caps liveness while giving 4
// independent chains of ILP.

typedef float v2f __attribute__((ext_vector_type(2)));

constexpr int ROWS = 32;   // pred rows per block tile (2 per iteration)
constexpr int COLS = 256;  // target cols per block (= blockDim.x)

// ---- CR-f32 sin/cos for |x|<=1 via double Taylor (trunc err < 1e-17) -----
__device__ __forceinline__ void sincos_cr(float rf, float* sf, float* cf) {
  double x = (double)rf;
  if (fabs(x) <= 1.0) {
    double z = x * x;
    double ps = -7.647163731819816e-13;
    ps = fma(ps, z, 1.605904383682161e-10);
    ps = fma(ps, z, -2.505210838544172e-08);
    ps = fma(ps, z, 2.755731922398589e-06);
    ps = fma(ps, z, -1.984126984126984e-04);
    ps = fma(ps, z, 8.333333333333333e-03);
    ps = fma(ps, z, -1.666666666666667e-01);
    double s = fma(ps * z, x, x);
    double pc = 1.561920696858623e-16;
    pc = fma(pc, z, -4.779477332387385e-14);
    pc = fma(pc, z, 1.147074559772972e-11);
    pc = fma(pc, z, -2.087675698786810e-09);
    pc = fma(pc, z, 2.755731922398589e-07);
    pc = fma(pc, z, -2.480158730158730e-05);
    pc = fma(pc, z, 1.388888888888889e-03);
    pc = fma(pc, z, -4.166666666666666e-02);
    pc = fma(pc, z, 5.000000000000000e-01);
    double c = fma(-pc, z, 1.0);
    *sf = (float)s;
    *cf = (float)c;
  } else {
    *sf = sinf(rf);       // f32 fallback: small footprint, never hit here
    *cf = cosf(rf);
  }
}

// ---- per-box params (s00, s01, s11, Vb): numpy-bit-identical f32 chain ---
__device__ __forceinline__ float4 box_params(const float* __restrict__ bx) {
#pragma clang fp contract(off)
  float w = fminf(fmaxf(bx[2], 1e-7f), 1e7f);
  float h = fminf(fmaxf(bx[3], 1e-7f), 1e7f);
  float s, c;
  sincos_cr(bx[4], &s, &c);
  float a = (0.5f * w) * (0.5f * w);
  float b = (0.5f * h) * (0.5f * h);
  float s00 = a * c * c + b * s * s;
  float s01 = (a - b) * s * c;
  float s11 = a * s * s + b * c * c;
  float det = s00 * s11 - s01 * s01;
  float vb  = 4.0f * __fsqrt_rn(fabsf(det));
  return make_float4(s00, s01, s11, vb);
}

// ---------------- fast faithful division helpers --------------------------
__device__ __forceinline__ v2f rcp_refined(v2f d) {
  v2f r;
  r[0] = __builtin_amdgcn_rcpf(d[0]);
  r[1] = __builtin_amdgcn_rcpf(d[1]);
  v2f one = {1.0f, 1.0f};
  v2f e = __builtin_elementwise_fma(-d, r, one);
  return __builtin_elementwise_fma(e, r, r);
}
__device__ __forceinline__ v2f div_faithful(v2f a, v2f d, v2f r) {
  v2f q = a * r;
  v2f e = __builtin_elementwise_fma(-d, q, a);
  return __builtin_elementwise_fma(e, r, q);
}

// ---------------- pair loss, 2 rows per call (packed f32) -----------------
__device__ __forceinline__ v2f kf_pair2(float4 p0, float4 p1, float4 t) {
#pragma clang fp contract(off)
  v2f px = {p0.x, p1.x};
  v2f py = {p0.y, p1.y};
  v2f pz = {p0.z, p1.z};
  v2f pw = {p0.w, p1.w};

  v2f m00 = px + t.x;
  v2f m01 = py + t.y;
  v2f m11 = pz + t.z;
  v2f det_m = m00 * m11 - m01 * m01;

  v2f r = rcp_refined(det_m);
  v2f i00 = div_faithful(m11, det_m, r);     // RULE 1
  v2f i01 = div_faithful(-m01, det_m, r);
  v2f i11 = div_faithful(m00, det_m, r);

  v2f k00 = px * i00 + py * i01;
  v2f k01 = px * i01 + py * i11;
  v2f k10 = py * i00 + pz * i01;
  v2f k11 = py * i01 + pz * i11;

  v2f sig00 = px - (k00 * px + k01 * py);
  v2f sig01 = py - (k00 * py + k01 * pz);
  v2f sig10 = py - (k10 * px + k11 * py);
  v2f sig11 = pz - (k10 * py + k11 * pz);

  v2f det_sig = sig00 * sig11 - sig01 * sig10;
  v2f vb;
  vb[0] = 4.0f * __builtin_amdgcn_sqrtf(fabsf(det_sig[0]));  // RULE 2
  vb[1] = 4.0f * __builtin_amdgcn_sqrtf(fabsf(det_sig[1]));

  v2f denom = pw + t.w - vb + 1e-6f;
  v2f kf;
  kf[0] = vb[0] * __builtin_amdgcn_rcpf(denom[0]);  // RULE 2: raw rcp
  kf[1] = vb[1] * __builtin_amdgcn_rcpf(denom[1]);

  v2f one = {1.0f, 1.0f};
  v2f res = one - kf;
  res[0] = fmaxf(res[0], 0.0f);
  res[1] = fmaxf(res[1], 0.0f);
  return res;
}

// ---- fused fast path: requires np % ROWS == 0 && nt % COLS == 0 ----------
__global__ __launch_bounds__(256, 4) void kf_loss_fused(
    const float* __restrict__ pred, const float* __restrict__ target,
    float* __restrict__ out, int nt) {
  __shared__ float4 sp[ROWS];

  const int tid  = threadIdx.x;
  const int row0 = blockIdx.x * ROWS;
  const int col0 = blockIdx.y * COLS;

  if (tid < ROWS) sp[tid] = box_params(pred + (size_t)(row0 + tid) * 5);
  const float4 t = box_params(target + (size_t)(col0 + tid) * 5);  // in-reg
  __syncthreads();

  float* o = out + (size_t)row0 * (size_t)nt + (size_t)(col0 + tid);

  #pragma unroll 4
  for (int rr = 0; rr < ROWS; rr += 2) {
    v2f res = kf_pair2(sp[rr], sp[rr + 1], t);   // LDS broadcast reads
    o[0] = res[0];
    o[(size_t)nt] = res[1];
    o += (size_t)2 * (size_t)nt;
  }
}

// ---- general-shape fallback (two-kernel, bounds-checked) -----------------
__global__ __launch_bounds__(256) void box_param_kernel(
    const float* __restrict__ pred, int np,
    const float* __restrict__ target, int nt,
    float4* __restrict__ ws) {
  int i = blockIdx.x * 256 + threadIdx.x;
  int n = np + nt;
  if (i >= n) return;
  const float* bx = (i < np) ? (pred + (size_t)i * 5)
                             : (target + (size_t)(i - np) * 5);
  ws[i] = box_params(bx);
}

__device__ __forceinline__ float rcp_ref_s(float d) {
  float r = __builtin_amdgcn_rcpf(d);
  return fmaf(fmaf(-d, r, 1.0f), r, r);
}
__device__ __forceinline__ float div_f_s(float a, float d, float r) {
  float q = a * r;
  return fmaf(fmaf(-d, q, a), r, q);
}
__device__ float kf_pair_s(float4 p, float4 t) {
#pragma clang fp contract(off)
  float m00 = p.x + t.x, m01 = p.y + t.y, m11 = p.z + t.z;
  float det_m = m00 * m11 - m01 * m01;
  float r = rcp_ref_s(det_m);
  float i00 = div_f_s(m11, det_m, r);
  float i01 = div_f_s(-m01, det_m, r);
  float i11 = div_f_s(m00, det_m, r);
  float k00 = p.x * i00 + p.y * i01;
  float k01 = p.x * i01 + p.y * i11;
  float k10 = p.y * i00 + p.z * i01;
  float k11 = p.y * i01 + p.z * i11;
  float sig00 = p.x - (k00 * p.x + k01 * p.y);
  float sig01 = p.y - (k00 * p.y + k01 * p.z);
  float sig10 = p.y - (k10 * p.x + k11 * p.y);
  float sig11 = p.z - (k10 * p.y + k11 * p.z);
  float det_sig = sig00 * sig11 - sig01 * sig10;
  float vb = 4.0f * __builtin_amdgcn_sqrtf(fabsf(det_sig));
  float denom = p.w + t.w - vb + 1e-6f;
  return fmaxf(1.0f - vb * __builtin_amdgcn_rcpf(denom), 0.0f);
}

__global__ __launch_bounds__(256) void kf_loss_edge(
    const float4* __restrict__ pp, const float4* __restrict__ tp,
    float* __restrict__ out, int np, int nt) {
  const int col  = blockIdx.y * COLS + threadIdx.x;
  const int row0 = blockIdx.x * ROWS;
  if (col >= nt) return;
  const float4 t = tp[col];
  int rend = ROWS;
  if (row0 + rend > np) rend = np - row0;
  float* o = out + (size_t)row0 * (size_t)nt + col;
  for (int rr = 0; rr < rend; ++rr) {
    *o = kf_pair_s(pp[row0 + rr], t);
    o += nt;
  }
}

extern "C" void kernel_launch(void* const* d_in, const int* in_sizes, int n_in,
                              void* d_out, int out_size, void* d_ws, size_t ws_size,
                              hipStream_t stream) {
  const float* pred   = (const float*)d_in[0];
  const float* target = (const float*)d_in[1];
  float* out = (float*)d_out;
  int np = in_sizes[0] / 5;
  int nt = in_sizes[1] / 5;

  if ((np % ROWS) == 0 && (nt % COLS) == 0) {
    dim3 grid(np / ROWS, nt / COLS);
    kf_loss_fused<<<grid, dim3(COLS), 0, stream>>>(pred, target, out, nt);
  } else {
    float4* params = (float4*)d_ws;
    int nbox = np + nt;
    box_param_kernel<<<(nbox + 255) / 256, 256, 0, stream>>>(
        pred, np, target, nt, params);
    dim3 grid((np + ROWS - 1) / ROWS, (nt + COLS - 1) / COLS);
    kf_loss_edge<<<grid, dim3(COLS), 0, stream>>>(
        params, params + np, out, np, nt);
  }
}

// Round 16
// 19.507 us; speedup vs baseline: 1.0160x; 1.0160x over previous
//
#include <hip/hip_runtime.h>
#include <cmath>

// KFIoU loss: pred (NP x 5), target (NT x 5) -> loss (NP x NT) f32.
//
// Numerics (established R1-R15): harness ref is a FLOAT32 numpy evaluation.
// Recipe: identical f32 op order, no fma contraction, correctly-rounded f32
// sin/cos (double Taylor for |r|<=1), and:
//   RULE 1 (upstream of det_sig cancellation: box params, i/k/sig chain):
//     CR-or-negligible-misround -> refined rcp + Markstein fma.
//   RULE 2 (downstream: sqrt, denom, final divide): 1-2 ulp invisible
//     (raw v_sqrt_f32 + raw v_rcp_f32 for denom; absmax bit-stable at
//     0.01171875 since R10).
//
// Perf (this round): cut issue-cycles per pair. Each thread owns TWO target
// columns; per 2-row iteration the packed p-registers (px..pw) are built
// once and feed TWO independent v2f chains (tA, tB) -> 4 pairs/iter:
// halves construction/LDS/loop overhead per pair, doubles ILP (covers
// rcp/sqrt trans-pipe latency in-wave), doubles stores per issue window.
// (256,2) cap: ~100 live VGPR for 2 chains, no spills.

typedef float v2f __attribute__((ext_vector_type(2)));

constexpr int ROWS  = 16;   // pred rows per block tile (2 per iteration)
constexpr int BCOLS = 512;  // target cols per block (2 per thread)

// ---- CR-f32 sin/cos for |x|<=1 via double Taylor (trunc err < 1e-17) -----
__device__ __forceinline__ void sincos_cr(float rf, float* sf, float* cf) {
  double x = (double)rf;
  if (fabs(x) <= 1.0) {
    double z = x * x;
    double ps = -7.647163731819816e-13;
    ps = fma(ps, z, 1.605904383682161e-10);
    ps = fma(ps, z, -2.505210838544172e-08);
    ps = fma(ps, z, 2.755731922398589e-06);
    ps = fma(ps, z, -1.984126984126984e-04);
    ps = fma(ps, z, 8.333333333333333e-03);
    ps = fma(ps, z, -1.666666666666667e-01);
    double s = fma(ps * z, x, x);
    double pc = 1.561920696858623e-16;
    pc = fma(pc, z, -4.779477332387385e-14);
    pc = fma(pc, z, 1.147074559772972e-11);
    pc = fma(pc, z, -2.087675698786810e-09);
    pc = fma(pc, z, 2.755731922398589e-07);
    pc = fma(pc, z, -2.480158730158730e-05);
    pc = fma(pc, z, 1.388888888888889e-03);
    pc = fma(pc, z, -4.166666666666666e-02);
    pc = fma(pc, z, 5.000000000000000e-01);
    double c = fma(-pc, z, 1.0);
    *sf = (float)s;
    *cf = (float)c;
  } else {
    *sf = sinf(rf);       // small-footprint fallback; never hit by this data
    *cf = cosf(rf);
  }
}

// ---- per-box params (s00, s01, s11, Vb): numpy-bit-identical f32 chain ---
__device__ __forceinline__ float4 box_params(const float* __restrict__ bx) {
#pragma clang fp contract(off)
  float w = fminf(fmaxf(bx[2], 1e-7f), 1e7f);
  float h = fminf(fmaxf(bx[3], 1e-7f), 1e7f);
  float s, c;
  sincos_cr(bx[4], &s, &c);
  float a = (0.5f * w) * (0.5f * w);
  float b = (0.5f * h) * (0.5f * h);
  float s00 = a * c * c + b * s * s;
  float s01 = (a - b) * s * c;
  float s11 = a * s * s + b * c * c;
  float det = s00 * s11 - s01 * s01;
  float vb  = 4.0f * __fsqrt_rn(fabsf(det));
  return make_float4(s00, s01, s11, vb);
}

// ---------------- fast faithful division helpers --------------------------
__device__ __forceinline__ v2f rcp_refined(v2f d) {
  v2f r;
  r[0] = __builtin_amdgcn_rcpf(d[0]);
  r[1] = __builtin_amdgcn_rcpf(d[1]);
  v2f one = {1.0f, 1.0f};
  v2f e = __builtin_elementwise_fma(-d, r, one);
  return __builtin_elementwise_fma(e, r, r);
}
__device__ __forceinline__ v2f div_faithful(v2f a, v2f d, v2f r) {
  v2f q = a * r;
  v2f e = __builtin_elementwise_fma(-d, q, a);
  return __builtin_elementwise_fma(e, r, q);
}

// ---- packed pair chain: rows packed in v2f, one target column ------------
__device__ __forceinline__ v2f kf_chain(v2f px, v2f py, v2f pz, v2f pw,
                                        float4 t) {
#pragma clang fp contract(off)
  v2f m00 = px + t.x;
  v2f m01 = py + t.y;
  v2f m11 = pz + t.z;
  v2f det_m = m00 * m11 - m01 * m01;

  v2f r = rcp_refined(det_m);
  v2f i00 = div_faithful(m11, det_m, r);     // RULE 1
  v2f i01 = div_faithful(-m01, det_m, r);
  v2f i11 = div_faithful(m00, det_m, r);

  v2f k00 = px * i00 + py * i01;
  v2f k01 = px * i01 + py * i11;
  v2f k10 = py * i00 + pz * i01;
  v2f k11 = py * i01 + pz * i11;

  v2f sig00 = px - (k00 * px + k01 * py);
  v2f sig01 = py - (k00 * py + k01 * pz);
  v2f sig10 = py - (k10 * px + k11 * py);
  v2f sig11 = pz - (k10 * py + k11 * pz);

  v2f det_sig = sig00 * sig11 - sig01 * sig10;
  v2f vb;
  vb[0] = 4.0f * __builtin_amdgcn_sqrtf(fabsf(det_sig[0]));  // RULE 2
  vb[1] = 4.0f * __builtin_amdgcn_sqrtf(fabsf(det_sig[1]));

  v2f denom = pw + t.w - vb + 1e-6f;
  v2f kf;
  kf[0] = vb[0] * __builtin_amdgcn_rcpf(denom[0]);  // RULE 2: raw rcp
  kf[1] = vb[1] * __builtin_amdgcn_rcpf(denom[1]);

  v2f one = {1.0f, 1.0f};
  v2f res = one - kf;
  res[0] = fmaxf(res[0], 0.0f);
  res[1] = fmaxf(res[1], 0.0f);
  return res;
}

// ---- fused fast path: requires np % ROWS == 0 && nt % BCOLS == 0 ---------
__global__ __launch_bounds__(256, 2) void kf_loss_fused(
    const float* __restrict__ pred, const float* __restrict__ target,
    float* __restrict__ out, int nt) {
  __shared__ float4 sp[ROWS];

  const int tid  = threadIdx.x;
  const int row0 = blockIdx.x * ROWS;
  const int col0 = blockIdx.y * BCOLS;

  if (tid < ROWS) sp[tid] = box_params(pred + (size_t)(row0 + tid) * 5);
  const int colA = col0 + tid;          // two columns per thread
  const int colB = colA + 256;
  const float4 tA = box_params(target + (size_t)colA * 5);
  const float4 tB = box_params(target + (size_t)colB * 5);
  __syncthreads();

  float* oA = out + (size_t)row0 * (size_t)nt + (size_t)colA;
  float* oB = oA + (size_t)nt;

  #pragma unroll
  for (int rr = 0; rr < ROWS; rr += 2) {
    float4 p0 = sp[rr];
    float4 p1 = sp[rr + 1];
    v2f px = {p0.x, p1.x};     // built ONCE, shared by both chains
    v2f py = {p0.y, p1.y};
    v2f pz = {p0.z, p1.z};
    v2f pw = {p0.w, p1.w};

    v2f ra = kf_chain(px, py, pz, pw, tA);   // two independent chains: ILP
    v2f rb = kf_chain(px, py, pz, pw, tB);

    oA[0]   = ra[0];
    oA[256] = rb[0];
    oB[0]   = ra[1];
    oB[256] = rb[1];
    oA += (size_t)2 * (size_t)nt;
    oB += (size_t)2 * (size_t)nt;
  }
}

// ---- general-shape fallback (two-kernel, bounds-checked) -----------------
__global__ __launch_bounds__(256) void box_param_kernel(
    const float* __restrict__ pred, int np,
    const float* __restrict__ target, int nt,
    float4* __restrict__ ws) {
  int i = blockIdx.x * 256 + threadIdx.x;
  int n = np + nt;
  if (i >= n) return;
  const float* bx = (i < np) ? (pred + (size_t)i * 5)
                             : (target + (size_t)(i - np) * 5);
  ws[i] = box_params(bx);
}

__device__ __forceinline__ float rcp_ref_s(float d) {
  float r = __builtin_amdgcn_rcpf(d);
  return fmaf(fmaf(-d, r, 1.0f), r, r);
}
__device__ __forceinline__ float div_f_s(float a, float d, float r) {
  float q = a * r;
  return fmaf(fmaf(-d, q, a), r, q);
}
__device__ float kf_pair_s(float4 p, float4 t) {
#pragma clang fp contract(off)
  float m00 = p.x + t.x, m01 = p.y + t.y, m11 = p.z + t.z;
  float det_m = m00 * m11 - m01 * m01;
  float r = rcp_ref_s(det_m);
  float i00 = div_f_s(m11, det_m, r);
  float i01 = div_f_s(-m01, det_m, r);
  float i11 = div_f_s(m00, det_m, r);
  float k00 = p.x * i00 + p.y * i01;
  float k01 = p.x * i01 + p.y * i11;
  float k10 = p.y * i00 + p.z * i01;
  float k11 = p.y * i01 + p.z * i11;
  float sig00 = p.x - (k00 * p.x + k01 * p.y);
  float sig01 = p.y - (k00 * p.y + k01 * p.z);
  float sig10 = p.y - (k10 * p.x + k11 * p.y);
  float sig11 = p.z - (k10 * p.y + k11 * p.z);
  float det_sig = sig00 * sig11 - sig01 * sig10;
  float vb = 4.0f * __builtin_amdgcn_sqrtf(fabsf(det_sig));
  float denom = p.w + t.w - vb + 1e-6f;
  return fmaxf(1.0f - vb * __builtin_amdgcn_rcpf(denom), 0.0f);
}

__global__ __launch_bounds__(256) void kf_loss_edge(
    const float4* __restrict__ pp, const float4* __restrict__ tp,
    float* __restrict__ out, int np, int nt) {
  const int col  = blockIdx.y * 256 + threadIdx.x;
  const int row0 = blockIdx.x * ROWS;
  if (col >= nt) return;
  const float4 t = tp[col];
  int rend = ROWS;
  if (row0 + rend > np) rend = np - row0;
  float* o = out + (size_t)row0 * (size_t)nt + col;
  for (int rr = 0; rr < rend; ++rr) {
    *o = kf_pair_s(pp[row0 + rr], t);
    o += nt;
  }
}

extern "C" void kernel_launch(void* const* d_in, const int* in_sizes, int n_in,
                              void* d_out, int out_size, void* d_ws, size_t ws_size,
                              hipStream_t stream) {
  const float* pred   = (const float*)d_in[0];
  const float* target = (const float*)d_in[1];
  float* out = (float*)d_out;
  int np = in_sizes[0] / 5;
  int nt = in_sizes[1] / 5;

  if ((np % ROWS) == 0 && (nt % BCOLS) == 0) {
    dim3 grid(np / ROWS, nt / BCOLS);
    kf_loss_fused<<<grid, dim3(256), 0, stream>>>(pred, target, out, nt);
  } else {
    float4* params = (float4*)d_ws;
    int nbox = np + nt;
    box_param_kernel<<<(nbox + 255) / 256, 256, 0, stream>>>(
        pred, np, target, nt, params);
    dim3 grid((np + ROWS - 1) / ROWS, (nt + 255) / 256);
    kf_loss_edge<<<grid, dim3(256), 0, stream>>>(
        params, params + np, out, np, nt);
  }
}